// Round 13
// baseline (15560.403 us; speedup 1.0000x reference)
//
#include <hip/hip_runtime.h>
#include <hip/hip_bf16.h>

// Stacked 2-layer Elman RNN, B=2048 T=256 H=512 OUT=1.
//
// Round-12 lesson: WRITE_SIZE 66-78MB every round since R6 = in-loop scratch
// spills. Scratch ops are buffer ops -> they enter the vmcnt ledger and the
// compiler's spill-reload waits DRAIN the hand-built prefetch queue (in-order
// retirement), so prefetch depth never mattered. Fix A: register diet /
// bigger tile so nothing spills (verify: WRITE < 5MB). Fix B: 64 blocks of
// BM=32 (8/XCD) halves the same-line L2 pile-up and doubles MFMA per loaded
// byte (each staged B-group feeds 2 row-tiles = 8 MFMAs).
//
//   64 blocks x 512 thr (8 waves, 2/SIMD, 256-VGPR budget, LDS 128KB=1/CU)
//   wave w owns col-tiles 4w..4w+3 and all 32 rows (2 row-tiles)
//   B-frags: inline-asm global_load_dwordx4 -> 4-slot VGPR ring, prefetch
//   distance 3, s_waitcnt vmcnt(12)+sched_barrier(0) only (no other in-loop
//   VMEM: x preloaded to LDS, no spills)
//   per-block kc-stagger koff=(bid&7)*2 decorrelates the 8 blocks/XCD
// Floor: 1.5MB/step/CU through L1 port (128B/cy) = 5.1us/step ~= 1.3ms.

typedef _Float16 half8 __attribute__((ext_vector_type(8)));
typedef float f32x4 __attribute__((ext_vector_type(4)));

#define T_STEPS 256
#define H_DIM   512
#define BM      32

#define BARRIER() do { \
    asm volatile("s_waitcnt lgkmcnt(0)" ::: "memory"); \
    __builtin_amdgcn_s_barrier(); \
    asm volatile("" ::: "memory"); \
  } while (0)

// B-fragment load: global -> VGPR quad, bypassing the compiler's vmcnt ledger
__device__ __forceinline__ half8 gld16(const half8* p){
  half8 r;
  asm volatile("global_load_dwordx4 %0, %1, off" : "=v"(r) : "v"(p));
  return r;
}

__device__ __forceinline__ float tanh_fast(float z){
  float az = fabsf(z);
  float e  = __expf(-2.0f * az);
  float r  = (1.0f - e) * __builtin_amdgcn_rcpf(1.0f + e);
  return copysignf(r, z);
}

// fp32 [k][n] -> fp16 MFMA-B fragments: out[(nt*16+kc)*64+lane] = 8 halves,
// col = nt*16 + (lane&15), k = kc*32 + (lane>>4)*8 + j
__global__ void prep_w_45028437131357(const float* __restrict__ W,
                                      half8* __restrict__ out){
  int tid  = blockIdx.x * 256 + threadIdx.x;
  int lane = tid & 63;
  int kc   = (tid >> 6) & 15;
  int nt   = tid >> 10;
  int col  = nt * 16 + (lane & 15);
  int k0   = kc * 32 + (lane >> 4) * 8;
  half8 v;
#pragma unroll
  for (int j = 0; j < 8; ++j) v[j] = (_Float16)W[(k0 + j) * H_DIM + col];
  out[tid] = v;
}

// LDS h layout: element (row, c) at byte  row*1024 + ((c*2) ^ ((row&7)<<4))

__global__ __launch_bounds__(512, 2)
void rnn_main_45028437131357(const float* __restrict__ x,
                             const float* __restrict__ Wx0,
                             const float* __restrict__ bx0,
                             const float* __restrict__ bh0,
                             const float* __restrict__ bx1,
                             const float* __restrict__ bh1,
                             const float* __restrict__ Wfc,
                             const float* __restrict__ bfc,
                             const half8* __restrict__ Wh0f,
                             const half8* __restrict__ Wx1f,
                             const half8* __restrict__ Wh1f,
                             float* __restrict__ out){
  __shared__ __align__(16) char  h0d[2][BM * 1024];    // 64 KB (double buf)
  __shared__ __align__(16) char  h1s[BM * 1024];       // 32 KB
  __shared__ __align__(16) float xall[BM * 256];       // 32 KB, swizzled
  // total 128 KB -> exactly 1 block/CU

  const int tid  = threadIdx.x;
  const int lane = tid & 63;
  const int w    = tid >> 6;            // 0..7, owns col-tiles 4w..4w+3
  const int w4   = 4 * w;
  const int r0   = blockIdx.x * BM;
  const int koff = (blockIdx.x & 7) * 2;    // stagger the 8 blocks/XCD

  // zero initial hidden state + preload x block (32 rows x 256 t) into LDS
  for (int i = tid; i < BM * 256; i += 512){
    ((float*)h0d[0])[i] = 0.0f;
    ((float*)h1s)[i] = 0.0f;
    int r = i >> 8, c = i & 255;
    xall[r * 256 + (c ^ ((r & 7) << 2))] = x[(r0 + r) * T_STEPS + c];
  }

  const int cl      = lane & 15;
  const int kg      = lane >> 4;
  const int aSwz    = (cl & 7) << 4;
  const int aOff0   = (cl)      * 1024 + kg * 16;   // row-tile 0
  const int aOff1   = (cl + 16) * 1024 + kg * 16;   // row-tile 1
  const int rowBase = kg * 4;

  // per-column constants for the 4 owned col-tiles
  float wx0c[4], b0c[4], b1c[4];
  int   colA[4];
#pragma unroll
  for (int i = 0; i < 4; ++i){
    int col = (w4 + i) * 16 + cl;
    colA[i] = col;
    wx0c[i] = Wx0[col];
    b0c[i]  = bx0[col] + bh0[col];
    b1c[i]  = bx1[col] + bh1[col];
  }

  // register ring: 4 slots x 4 fragments (indices constant after unroll)
  half8 rb[4][4];

  // STAGE(G): groups 0-15 Wh0, 16-31 Wh1, 32-47 Wx1; wraps at 48.
#define STAGE(G)                                                              \
  {                                                                           \
    int g48 = ((G) >= 48) ? (G) - 48 : (G);                                   \
    const half8* M = (g48 < 16) ? Wh0f : ((g48 < 32) ? Wh1f : Wx1f);          \
    int keff = ((g48 & 15) + koff) & 15;                                      \
    const half8* base = M + keff * 64 + lane;                                 \
    rb[(G) & 3][0] = gld16(base + (w4 + 0) * 1024);                           \
    rb[(G) & 3][1] = gld16(base + (w4 + 1) * 1024);                           \
    rb[(G) & 3][2] = gld16(base + (w4 + 2) * 1024);                           \
    rb[(G) & 3][3] = gld16(base + (w4 + 3) * 1024);                           \
  }

  // CONSUME: 2 A-frag ds_reads issued BEFORE the counted wait; MFMAs pinned
  // below the wait by sched_barrier(0) (rule #18).
#define CONSUME(APTR, AC, KC, G)                                              \
  {                                                                           \
    int kb = (((KC) + koff) & 15) * 64;                                       \
    half8 a0 = *(const half8*)((APTR) + ((aOff0 + kb) ^ aSwz));               \
    half8 a1 = *(const half8*)((APTR) + ((aOff1 + kb) ^ aSwz));               \
    asm volatile("s_waitcnt vmcnt(12)");                                      \
    __builtin_amdgcn_sched_barrier(0);                                        \
    AC[0][0] = __builtin_amdgcn_mfma_f32_16x16x32_f16(a0, rb[(G)&3][0], AC[0][0], 0,0,0); \
    AC[0][1] = __builtin_amdgcn_mfma_f32_16x16x32_f16(a0, rb[(G)&3][1], AC[0][1], 0,0,0); \
    AC[0][2] = __builtin_amdgcn_mfma_f32_16x16x32_f16(a0, rb[(G)&3][2], AC[0][2], 0,0,0); \
    AC[0][3] = __builtin_amdgcn_mfma_f32_16x16x32_f16(a0, rb[(G)&3][3], AC[0][3], 0,0,0); \
    AC[1][0] = __builtin_amdgcn_mfma_f32_16x16x32_f16(a1, rb[(G)&3][0], AC[1][0], 0,0,0); \
    AC[1][1] = __builtin_amdgcn_mfma_f32_16x16x32_f16(a1, rb[(G)&3][1], AC[1][1], 0,0,0); \
    AC[1][2] = __builtin_amdgcn_mfma_f32_16x16x32_f16(a1, rb[(G)&3][2], AC[1][2], 0,0,0); \
    AC[1][3] = __builtin_amdgcn_mfma_f32_16x16x32_f16(a1, rb[(G)&3][3], AC[1][3], 0,0,0); \
  }

  // clean ledger, then prime the ring (prefetch distance 3)
  asm volatile("s_waitcnt vmcnt(0)" ::: "memory");
  STAGE(0); STAGE(1); STAGE(2);

  const f32x4 z4 = {0.f, 0.f, 0.f, 0.f};
  int s = 0;

  for (int t = 0; t < T_STEPS; ++t){
    BARRIER();                            // B0: h1_new(t-1), h0, xall visible

    const char* h0cur = h0d[s];
    char*       h0nxt = h0d[s ^ 1];

    f32x4 acc0[2][4] = {{z4,z4,z4,z4},{z4,z4,z4,z4}};
    f32x4 acc1[2][4] = {{z4,z4,z4,z4},{z4,z4,z4,z4}};

    // ---- A0: acc0 += h0_old @ Wh0 (groups 0..15) ----
#pragma unroll
    for (int kc = 0; kc < 16; ++kc){
      STAGE(kc + 3);
      CONSUME(h0cur, acc0, kc, kc);
    }
    // ---- A1: acc1 += h1_old @ Wh1 (groups 16..31) ----
#pragma unroll
    for (int kc = 0; kc < 16; ++kc){
      STAGE(kc + 19);
      CONSUME(h1s, acc1, kc, kc + 16);
    }

    // epilogue0: nh0 = tanh(acc0 + b0 + x*wx0) -> h0d[s^1]
#pragma unroll
    for (int rt = 0; rt < 2; ++rt){
      float xv[4];
#pragma unroll
      for (int rg = 0; rg < 4; ++rg){
        int row = rt * 16 + rowBase + rg;
        xv[rg] = xall[row * 256 + (t ^ ((row & 7) << 2))];
      }
#pragma unroll
      for (int i = 0; i < 4; ++i)
#pragma unroll
        for (int rg = 0; rg < 4; ++rg){
          float z = acc0[rt][i][rg] + b0c[i] + xv[rg] * wx0c[i];
          int row = rt * 16 + rowBase + rg;
          *(_Float16*)(h0nxt + row * 1024 +
                       ((colA[i] * 2) ^ ((row & 7) << 4))) = (_Float16)tanh_fast(z);
        }
    }
    BARRIER();                            // B2: h0_new visible; A reads done

    // ---- B: acc1 += h0_new @ Wx1 (groups 32..47; stages wrap 48..50) ----
#pragma unroll
    for (int kc = 0; kc < 16; ++kc){
      STAGE(kc + 35);
      CONSUME(h0nxt, acc1, kc, kc + 32);
    }

    // epilogue1: h1_new = tanh(acc1 + b1) -> h1s
#pragma unroll
    for (int rt = 0; rt < 2; ++rt)
#pragma unroll
      for (int i = 0; i < 4; ++i)
#pragma unroll
        for (int rg = 0; rg < 4; ++rg){
          int row = rt * 16 + rowBase + rg;
          *(_Float16*)(h1s + row * 1024 +
                       ((colA[i] * 2) ^ ((row & 7) << 4))) =
              (_Float16)tanh_fast(acc1[rt][i][rg] + b1c[i]);
        }
    s ^= 1;
  }
#undef STAGE
#undef CONSUME

  asm volatile("s_waitcnt vmcnt(0)" ::: "memory");   // drain wrapped prefetch
  BARRIER();

  // ---- final FC: out[r] = h1[r,:] . Wfc + bfc ----
  {
    int r  = tid >> 4;        // 0..31
    int g2 = tid & 15;
    float p = 0.0f;
#pragma unroll
    for (int k2 = 0; k2 < 32; ++k2){
      int c = g2 + 16 * k2;
      float hv = (float)*(const _Float16*)(h1s + r * 1024 +
                                           ((c * 2) ^ ((r & 7) << 4)));
      p += hv * Wfc[c];
    }
#pragma unroll
    for (int off = 8; off >= 1; off >>= 1) p += __shfl_xor(p, off);
    if (g2 == 0) out[r0 + r] = p + bfc[0];
  }
}

extern "C" void kernel_launch(void* const* d_in, const int* in_sizes, int n_in,
                              void* d_out, int out_size, void* d_ws, size_t ws_size,
                              hipStream_t stream) {
  const float* x   = (const float*)d_in[0];
  const float* Wx0 = (const float*)d_in[1];
  const float* bx0 = (const float*)d_in[2];
  const float* Wh0 = (const float*)d_in[3];
  const float* bh0 = (const float*)d_in[4];
  const float* Wx1 = (const float*)d_in[5];
  const float* bx1 = (const float*)d_in[6];
  const float* Wh1 = (const float*)d_in[7];
  const float* bh1 = (const float*)d_in[8];
  const float* Wfc = (const float*)d_in[9];
  const float* bfc = (const float*)d_in[10];

  _Float16* wsH = (_Float16*)d_ws;
  half8* Wh0f = (half8*)(wsH);
  half8* Wx1f = (half8*)(wsH + 262144);
  half8* Wh1f = (half8*)(wsH + 524288);

  prep_w_45028437131357<<<128, 256, 0, stream>>>(Wh0, Wh0f);
  prep_w_45028437131357<<<128, 256, 0, stream>>>(Wx1, Wx1f);
  prep_w_45028437131357<<<128, 256, 0, stream>>>(Wh1, Wh1f);

  rnn_main_45028437131357<<<64, 512, 0, stream>>>(
      x, Wx0, bx0, bh0, bx1, bh1, Wfc, bfc,
      (const half8*)Wh0f, (const half8*)Wx1f, (const half8*)Wh1f,
      (float*)d_out);
}